// Round 18
// baseline (271.930 us; speedup 1.0000x reference)
//
#include <hip/hip_runtime.h>

// Workspace float offsets
#define F_TH    0u          // bf16 theta[8][4096][128]   -> 2,097,152 f
#define F_PHIB  2097152u    // bf16 phi[8][1024][128]     ->   524,288 f
#define F_GB    2621440u    // bf16 g[8][256][1024]       -> 1,048,576 f
// total 3,670,016 floats = 14.7 MB

typedef __attribute__((ext_vector_type(4))) float f32x4;
typedef __attribute__((ext_vector_type(8))) short bf16x8;

__device__ __forceinline__ unsigned short f2bf(float f) {
  union { unsigned int i; float f; } x; x.f = f;
  unsigned int r = x.i + 0x7fffu + ((x.i >> 16) & 1u);
  return (unsigned short)(r >> 16);
}
__device__ __forceinline__ unsigned int pk2(float a, float b) {
  return (unsigned int)f2bf(a) | ((unsigned int)f2bf(b) << 16);
}
__device__ __forceinline__ void gload_lds16(const void* g, void* l) {
  __builtin_amdgcn_global_load_lds(
      (const __attribute__((address_space(1))) unsigned int*)g,
      (__attribute__((address_space(3))) unsigned int*)l, 16, 0, 0);
}

// ---------------------------------------------------------------------------
// Fused front-end: x (f32 [b][512][4096]) -> theta[b][n][i] bf16,
// pooled phi[b][m][i] bf16, pooled g[b][d][m] bf16 — reads x exactly once.
// (unchanged from R14)
// ---------------------------------------------------------------------------
__global__ __launch_bounds__(512)
void k_front(const float* __restrict__ x,
             const float* __restrict__ tw, const float* __restrict__ tb,
             const float* __restrict__ pw, const float* __restrict__ pb,
             const float* __restrict__ gw, const float* __restrict__ gb,
             float* __restrict__ ws) {
  const int nt = blockIdx.x, b = blockIdx.y;
  const int n0 = nt * 128;
  const int tid = threadIdx.x;
  const int w = tid >> 6, lane = tid & 63, q = lane >> 4, col = lane & 15;

  __shared__ uint4 ldsb[5888];      // 94,208 B
  char* lds = (char*)ldsb;
  char* xs  = lds;                  // [64 ch][512B] f32, swz ((ch&7)<<4)
  char* Xm  = lds + 32768;          // [128 n][80B] bf16 (32 c)
  char* Xg0 = lds + 43008;
  char* Xg1 = lds + 53248;
  char* Wt  = lds + 63488;          // [128 o][80B]
  char* Wp  = lds + 73728;
  char* Wg  = lds + 83968;

  f32x4 at[8], ap[8], a0[8], a1[8];
#pragma unroll
  for (int j = 0; j < 8; ++j) {
    at[j] = (f32x4){0.f, 0.f, 0.f, 0.f};
    ap[j] = (f32x4){0.f, 0.f, 0.f, 0.f};
    a0[j] = (f32x4){0.f, 0.f, 0.f, 0.f};
    a1[j] = (f32x4){0.f, 0.f, 0.f, 0.f};
  }

  for (int kc = 0; kc < 8; ++kc) {
    {
      const int ch = tid >> 5;               // 0..15
      const int so = (tid & 31) * 16;        // byte within 512B row
#pragma unroll
      for (int i = 0; i < 4; ++i) {
        const int chh = 16 * i + ch;
        const float* src = x + ((size_t)(b * 512 + 64 * kc + chh)) * 4096 + n0;
        gload_lds16((const char*)src + (so ^ ((chh & 7) << 4)),
                    xs + 8192 * i + tid * 16);
      }
      const int o = tid >> 2, c4 = tid & 3;
      const size_t wo = (size_t)o * 256 + 32 * kc + 8 * c4;
      float4 t0 = ((const float4*)(tw + wo))[0], t1 = ((const float4*)(tw + wo))[1];
      float4 p0 = ((const float4*)(pw + wo))[0], p1 = ((const float4*)(pw + wo))[1];
      float4 g0 = ((const float4*)(gw + wo))[0], g1 = ((const float4*)(gw + wo))[1];
      *(uint4*)(Wt + o * 80 + 16 * c4) =
          make_uint4(pk2(t0.x, t0.y), pk2(t0.z, t0.w), pk2(t1.x, t1.y), pk2(t1.z, t1.w));
      *(uint4*)(Wp + o * 80 + 16 * c4) =
          make_uint4(pk2(p0.x, p0.y), pk2(p0.z, p0.w), pk2(p1.x, p1.y), pk2(p1.z, p1.w));
      *(uint4*)(Wg + o * 80 + 16 * c4) =
          make_uint4(pk2(g0.x, g0.y), pk2(g0.z, g0.w), pk2(g1.x, g1.y), pk2(g1.z, g1.w));
    }
    __syncthreads();
    {
      const int n = tid >> 2, c4 = tid & 3;
      unsigned um[4], u0[4], u1[4];
#pragma unroll
      for (int s = 0; s < 4; ++s) {
        float v[4];
#pragma unroll
        for (int e = 0; e < 2; ++e) {
          const int cp = 8 * c4 + 2 * s + e;   // c' 0..31
          const int l0 = 2 * cp, l1 = 2 * cp + 1;
          v[2 * e]     = *(const float*)(xs + l0 * 512 + ((n * 4) ^ ((l0 & 7) << 4)));
          v[2 * e + 1] = *(const float*)(xs + l1 * 512 + ((n * 4) ^ ((l1 & 7) << 4)));
        }
        um[s] = pk2(0.5f * (v[0] + v[1]), 0.5f * (v[2] + v[3]));
        u0[s] = pk2(v[0], v[2]);
        u1[s] = pk2(v[1], v[3]);
      }
      *(uint4*)(Xm  + n * 80 + 16 * c4) = make_uint4(um[0], um[1], um[2], um[3]);
      *(uint4*)(Xg0 + n * 80 + 16 * c4) = make_uint4(u0[0], u0[1], u0[2], u0[3]);
      *(uint4*)(Xg1 + n * 80 + 16 * c4) = make_uint4(u1[0], u1[1], u1[2], u1[3]);
    }
    __syncthreads();
    {
      const int ar = 16 * w + col;
      const bf16x8 aft = *(const bf16x8*)(Wt + ar * 80 + 16 * q);
      const bf16x8 afp = *(const bf16x8*)(Wp + ar * 80 + 16 * q);
      const bf16x8 afg = *(const bf16x8*)(Wg + ar * 80 + 16 * q);
#pragma unroll
      for (int j = 0; j < 8; ++j) {
        const int br = 16 * j + col;
        const bf16x8 bm = *(const bf16x8*)(Xm  + br * 80 + 16 * q);
        const bf16x8 b0 = *(const bf16x8*)(Xg0 + br * 80 + 16 * q);
        const bf16x8 b1 = *(const bf16x8*)(Xg1 + br * 80 + 16 * q);
        at[j] = __builtin_amdgcn_mfma_f32_16x16x32_bf16(aft, bm, at[j], 0, 0, 0);
        ap[j] = __builtin_amdgcn_mfma_f32_16x16x32_bf16(afp, bm, ap[j], 0, 0, 0);
        a0[j] = __builtin_amdgcn_mfma_f32_16x16x32_bf16(afg, b0, a0[j], 0, 0, 0);
        a1[j] = __builtin_amdgcn_mfma_f32_16x16x32_bf16(afg, b1, a1[j], 0, 0, 0);
      }
    }
    __syncthreads();
  }

  const int o0 = 16 * w + 4 * q;
  const int mb = (nt >> 3) * 256 + (nt & 7) * 32;

  {
    float bst[4];
#pragma unroll
    for (int r = 0; r < 4; ++r) bst[r] = tb[o0 + r];
#pragma unroll
    for (int j = 0; j < 8; ++j) {
      const int n = 16 * j + col;
      uint2 pkk = make_uint2(pk2(at[j][0] + bst[0], at[j][1] + bst[1]),
                             pk2(at[j][2] + bst[2], at[j][3] + bst[3]));
      *(uint2*)(xs + n * 256 + ((2 * o0) ^ ((n & 7) << 4))) = pkk;
    }
  }

  {
    float bsp[4];
#pragma unroll
    for (int r = 0; r < 4; ++r) bsp[r] = pb[o0 + r];
    unsigned short* phiB = (unsigned short*)(ws + F_PHIB);
#pragma unroll
    for (int jj = 0; jj < 4; ++jj) {
      const int j = (jj >> 1) * 4 + (jj & 1);   // {0,1,4,5}
      f32x4 pm;
#pragma unroll
      for (int r = 0; r < 4; ++r) pm[r] = fmaxf(ap[j][r], ap[j + 2][r]);
#pragma unroll
      for (int r = 0; r < 4; ++r) pm[r] = fmaxf(pm[r], __shfl_xor(pm[r], 1));
      if ((col & 1) == 0) {
        const int vp = 8 * (j & 1) + (col >> 1);
        const int m = mb + 16 * (j >> 2) + vp;
        uint2 pkk = make_uint2(pk2(pm[0] + bsp[0], pm[1] + bsp[1]),
                               pk2(pm[2] + bsp[2], pm[3] + bsp[3]));
        *(uint2*)(phiB + ((size_t)(b * 1024) + m) * 128 + o0) = pkk;
      }
    }
  }

  {
    float bsg[4];
#pragma unroll
    for (int r = 0; r < 4; ++r) bsg[r] = gb[o0 + r];
#pragma unroll
    for (int gr = 0; gr < 2; ++gr) {
      char* pt = gr ? Xg1 : Xg0;
      const f32x4* ag = gr ? a1 : a0;
#pragma unroll
      for (int jj = 0; jj < 4; ++jj) {
        const int j = (jj >> 1) * 4 + (jj & 1);
        f32x4 pm;
#pragma unroll
        for (int r = 0; r < 4; ++r) pm[r] = fmaxf(ag[j][r], ag[j + 2][r]);
#pragma unroll
        for (int r = 0; r < 4; ++r) pm[r] = fmaxf(pm[r], __shfl_xor(pm[r], 1));
        if ((col & 1) == 0) {
          const int ml = 16 * (j >> 2) + 8 * (j & 1) + (col >> 1);
#pragma unroll
          for (int r = 0; r < 4; ++r)
            *(unsigned short*)(pt + (o0 + r) * 80 + ml * 2) = f2bf(pm[r] + bsg[r]);
        }
      }
    }
  }
  __syncthreads();

  {
    const int n = tid >> 2, seg = tid & 3;
    unsigned short* dst = (unsigned short*)(ws + F_TH) +
                          ((size_t)(b * 4096) + n0 + n) * 128 + seg * 32;
    const char* row = xs + n * 256;
    const int sw = (n & 7) << 4;
#pragma unroll
    for (int k = 0; k < 4; ++k)
      ((uint4*)dst)[k] = *(const uint4*)(row + ((64 * seg + 16 * k) ^ sw));
  }
  if (tid < 256) {
    const int o = tid >> 1, gr = tid & 1;
    const char* row = (gr ? Xg1 : Xg0) + o * 80;
    unsigned short* dst = (unsigned short*)(ws + F_GB) +
                          ((size_t)(b * 256) + 2 * o + gr) * 1024 + mb;
#pragma unroll
    for (int k = 0; k < 4; ++k)
      ((uint4*)dst)[k] = *(const uint4*)(row + 16 * k);
  }
}

// ---------------------------------------------------------------------------
// MFMA flash attention (R13 loop) + fused final W conv + bias + residual.
// Epilogue = R15 structure; out stores and residual x loads use non-temporal
// hints (out never re-read; x dead after this read) to keep phi/g/theta
// resident in L2. Non-temporal ops use f32x4 (ext_vector_type) — HIP float4
// is rejected by the builtin.
// ---------------------------------------------------------------------------
#define NSIT 16
__global__ __launch_bounds__(512)
void k_attn_mfma(const float* __restrict__ x,
                 const float* __restrict__ Ww, const float* __restrict__ Wb,
                 float* __restrict__ ws, float* __restrict__ out) {
  const int b = blockIdx.x;          // 8 batches -> 8 XCDs (round-robin)
  const int n0 = blockIdx.y * 128;
  const int tid = threadIdx.x;
  const int w = tid >> 6;
  const int lane = tid & 63;
  const int q = lane >> 4;
  const int col = lane & 15;
  const int ksw = (col & 7) << 4;

  __shared__ char lds[131072];
  char* plw0 = lds + 98304 + w * 4096;
  char* plw1 = plw0 + 2048;

  const unsigned short* thetaB = (const unsigned short*)(ws + F_TH);
  const char* phiBb = (const char*)((const unsigned short*)(ws + F_PHIB) + (size_t)b * 1024 * 128);
  const char* gBb   = (const char*)((const unsigned short*)(ws + F_GB) + (size_t)b * 256 * 1024);

  const int kr0 = lane >> 4;
  const int kso = (lane & 15) * 16;
  const int vr0 = lane >> 3;
  const int vso = (lane & 7) * 16;

  bf16x8 qf[4];
  {
    const unsigned short* qp = thetaB + ((size_t)(b * 4096 + n0 + 16 * w + col)) * 128 + 8 * q;
#pragma unroll
    for (int c = 0; c < 4; ++c) qf[c] = *(const bf16x8*)(qp + 32 * c);
  }

  f32x4 ot[16];
#pragma unroll
  for (int t = 0; t < 16; ++t) ot[t] = (f32x4){0.f, 0.f, 0.f, 0.f};
  float mrun = -1e30f, lsum = 0.f;

  {
    const int r = 4 * w + kr0;
    gload_lds16(phiBb + (size_t)r * 256 + (kso ^ ((r & 7) << 4)), lds + w * 1024);
    gload_lds16(phiBb + (size_t)(32 + r) * 256 + (kso ^ ((r & 7) << 4)),
                lds + 8192 + w * 1024);
#pragma unroll
    for (int j = 0; j < 4; ++j) {
      const int c = 4 * w + j;
      const int d = 8 * c + vr0;
      gload_lds16(gBb + (size_t)d * 2048 + (vso ^ ((d & 7) << 4)),
                  lds + 32768 + c * 1024);
    }
  }
  __syncthreads();

  for (int sit = 0; sit < NSIT; ++sit) {
    char* kt0 = lds + ((2 * sit) & 3) * 8192;
    char* kt1 = lds + ((2 * sit + 1) & 3) * 8192;
    char* vtc = lds + 32768 + (sit & 1) * 32768;

    if (sit + 1 < NSIT) {
      const int r = 4 * w + kr0;
      const int swk = (kso ^ ((r & 7) << 4));
      gload_lds16(phiBb + (size_t)((2 * sit + 2) * 32 + r) * 256 + swk,
                  lds + ((2 * sit + 2) & 3) * 8192 + w * 1024);
      gload_lds16(phiBb + (size_t)((2 * sit + 3) * 32 + r) * 256 + swk,
                  lds + ((2 * sit + 3) & 3) * 8192 + w * 1024);
      const size_t vm = (size_t)((sit + 1) * 64) * 2;
#pragma unroll
      for (int j = 0; j < 4; ++j) {
        const int c = 4 * w + j;
        const int d = 8 * c + vr0;
        gload_lds16(gBb + (size_t)d * 2048 + vm + (vso ^ ((d & 7) << 4)),
                    lds + 32768 + ((sit & 1) ^ 1) * 32768 + c * 1024);
      }
    }

    f32x4 st0[2], st1[2];
#pragma unroll
    for (int s = 0; s < 2; ++s) {
      st0[s] = (f32x4){0.f, 0.f, 0.f, 0.f};
      st1[s] = (f32x4){0.f, 0.f, 0.f, 0.f};
    }
    __builtin_amdgcn_s_setprio(1);
#pragma unroll
    for (int c = 0; c < 4; ++c)
#pragma unroll
      for (int s = 0; s < 2; ++s) {
        const bf16x8 kf0 = *(const bf16x8*)(kt0 + (16 * s + col) * 256 +
                                            ((64 * c + 16 * q) ^ ksw));
        const bf16x8 kf1 = *(const bf16x8*)(kt1 + (16 * s + col) * 256 +
                                            ((64 * c + 16 * q) ^ ksw));
        st0[s] = __builtin_amdgcn_mfma_f32_16x16x32_bf16(kf0, qf[c], st0[s], 0, 0, 0);
        st1[s] = __builtin_amdgcn_mfma_f32_16x16x32_bf16(kf1, qf[c], st1[s], 0, 0, 0);
      }
    __builtin_amdgcn_s_setprio(0);

    float pmax = -1e30f;
#pragma unroll
    for (int s = 0; s < 2; ++s)
#pragma unroll
      for (int r = 0; r < 4; ++r) {
        pmax = fmaxf(pmax, st0[s][r]);
        pmax = fmaxf(pmax, st1[s][r]);
      }
    pmax = fmaxf(pmax, __shfl_xor(pmax, 16));
    pmax = fmaxf(pmax, __shfl_xor(pmax, 32));
    if (!__all(pmax - mrun <= 8.f)) {
      const float mnew = fmaxf(mrun, pmax);
      const float scl = __expf(mrun - mnew);
      mrun = mnew;
      lsum *= scl;
#pragma unroll
      for (int t = 0; t < 16; ++t) {
        ot[t][0] *= scl; ot[t][1] *= scl; ot[t][2] *= scl; ot[t][3] *= scl;
      }
    }
    float rsum = 0.f;
#pragma unroll
    for (int s = 0; s < 2; ++s)
#pragma unroll
      for (int r = 0; r < 4; ++r) {
        st0[s][r] = __expf(st0[s][r] - mrun);
        st1[s][r] = __expf(st1[s][r] - mrun);
        rsum += st0[s][r] + st1[s][r];
      }
    rsum += __shfl_xor(rsum, 16);
    rsum += __shfl_xor(rsum, 32);
    lsum += rsum;

    char* prow0 = plw0 + col * 128;
    char* prow1 = plw1 + col * 128;
#pragma unroll
    for (int s = 0; s < 2; ++s)
#pragma unroll
      for (int hp = 0; hp < 2; ++hp) {
        *(unsigned int*)(prow0 + ((32 * s + 8 * q + 4 * hp) ^ ksw)) =
            pk2(st0[s][2 * hp], st0[s][2 * hp + 1]);
        *(unsigned int*)(prow1 + ((32 * s + 8 * q + 4 * hp) ^ ksw)) =
            pk2(st1[s][2 * hp], st1[s][2 * hp + 1]);
      }
    const bf16x8 pf0 = *(const bf16x8*)(prow0 + ((16 * q) ^ ksw));
    const bf16x8 pf1 = *(const bf16x8*)(prow1 + ((16 * q) ^ ksw));

    __builtin_amdgcn_s_setprio(1);
#pragma unroll
    for (int t = 0; t < 16; ++t) {
      const int d = 16 * t + col;
      const int dsw = (d & 7) << 4;
      const bf16x8 vf0 = *(const bf16x8*)(vtc + d * 128 + ((16 * q) ^ dsw));
      ot[t] = __builtin_amdgcn_mfma_f32_16x16x32_bf16(vf0, pf0, ot[t], 0, 0, 0);
    }
#pragma unroll
    for (int t = 0; t < 16; ++t) {
      const int d = 16 * t + col;
      const int dsw = (d & 7) << 4;
      const bf16x8 vf1 = *(const bf16x8*)(vtc + d * 128 + ((64 + 16 * q) ^ dsw));
      ot[t] = __builtin_amdgcn_mfma_f32_16x16x32_bf16(vf1, pf1, ot[t], 0, 0, 0);
    }
    __builtin_amdgcn_s_setprio(0);

    __syncthreads();
  }

  // ---- write normalized y tile to LDS (B-fragment layout) ----
  const float inv = 1.f / lsum;
  char* yt = lds;
  {
    const int nl = 16 * w + col;
    const int swn = (nl & 7) << 4;
#pragma unroll
    for (int t = 0; t < 16; ++t) {
      const unsigned int w0 = pk2(ot[t][0] * inv, ot[t][2] * inv);
      const unsigned int w1 = pk2(ot[t][1] * inv, ot[t][3] * inv);
      const int bo = 16 * t + 4 * q;
      *(unsigned int*)(yt + nl * 256 + (bo ^ swn)) = w0;
      *(unsigned int*)(yt + (128 + nl) * 256 + (bo ^ swn)) = w1;
    }
  }
  __syncthreads();

  // ---- fused W conv: facc[gr][h][j] = sum_i Ww[32w+16h+col][i] * y[gr][n][i]
  f32x4 facc[2][2][8];
#pragma unroll
  for (int gr = 0; gr < 2; ++gr)
#pragma unroll
    for (int h = 0; h < 2; ++h)
#pragma unroll
      for (int j = 0; j < 8; ++j) facc[gr][h][j] = (f32x4){0.f, 0.f, 0.f, 0.f};

#pragma unroll
  for (int gr = 0; gr < 2; ++gr) {
#pragma unroll
    for (int c = 0; c < 4; ++c) {
      bf16x8 bfr[8];
#pragma unroll
      for (int j = 0; j < 8; ++j) {
        const int nl = 16 * j + col;
        bfr[j] = *(const bf16x8*)(yt + (128 * gr + nl) * 256 + ((64 * c + 16 * q) ^ ksw));
      }
#pragma unroll
      for (int h = 0; h < 2; ++h) {
        const int o = 32 * w + 16 * h + col;
        const float* wp = Ww + (size_t)o * 128 + 32 * c + 8 * q;
        const float4 w0 = ((const float4*)wp)[0];
        const float4 w1 = ((const float4*)wp)[1];
        union { unsigned u[4]; bf16x8 v; } af;
        af.u[0] = pk2(w0.x, w0.y); af.u[1] = pk2(w0.z, w0.w);
        af.u[2] = pk2(w1.x, w1.y); af.u[3] = pk2(w1.z, w1.w);
#pragma unroll
        for (int j = 0; j < 8; ++j)
          facc[gr][h][j] = __builtin_amdgcn_mfma_f32_16x16x32_bf16(af.v, bfr[j], facc[gr][h][j], 0, 0, 0);
      }
    }
  }
  __syncthreads();   // all waves done reading yt; LDS free for f32 transpose

  // ---- per-group f32 transpose + bias + residual + coalesced store ----
  char* ft = lds;    // [256 o][512B], swz ((o&7)<<4)  = 128KB
#pragma unroll
  for (int gr = 0; gr < 2; ++gr) {
#pragma unroll
    for (int h = 0; h < 2; ++h) {
      const int o0 = 32 * w + 16 * h + 4 * q;
#pragma unroll
      for (int j = 0; j < 8; ++j) {
        const int n = 16 * j + col;
#pragma unroll
        for (int r = 0; r < 4; ++r)
          *(float*)(ft + (o0 + r) * 512 + ((n * 4) ^ (((o0 + r) & 7) << 4))) =
              facc[gr][h][j][r];
      }
    }
    __syncthreads();
    {
      const int o = tid >> 1, h2 = tid & 1;
      const float bsv = Wb[o];
      const int ch = 2 * o + gr;
      const size_t base = ((size_t)(b * 512 + ch)) * 4096 + n0 + h2 * 64;
      const char* row = ft + o * 512;
      const int sw = (o & 7) << 4;
#pragma unroll
      for (int k = 0; k < 16; ++k) {
        f32x4 v = *(const f32x4*)(row + ((256 * h2 + 16 * k) ^ sw));
        const f32x4 xa = __builtin_nontemporal_load((const f32x4*)(x + base) + k);
        f32x4 o4;
        o4[0] = v[0] + bsv + xa[0];
        o4[1] = v[1] + bsv + xa[1];
        o4[2] = v[2] + bsv + xa[2];
        o4[3] = v[3] + bsv + xa[3];
        __builtin_nontemporal_store(o4, (f32x4*)(out + base) + k);
      }
    }
    if (gr == 0) __syncthreads();
  }
}

extern "C" void kernel_launch(void* const* d_in, const int* in_sizes, int n_in,
                              void* d_out, int out_size, void* d_ws, size_t ws_size,
                              hipStream_t stream) {
  const float* x  = (const float*)d_in[0];
  const float* gw = (const float*)d_in[1];
  const float* gb = (const float*)d_in[2];
  const float* tw = (const float*)d_in[3];
  const float* tb = (const float*)d_in[4];
  const float* pw = (const float*)d_in[5];
  const float* pb = (const float*)d_in[6];
  const float* Ww = (const float*)d_in[7];
  const float* Wb = (const float*)d_in[8];
  float* out = (float*)d_out;
  float* ws  = (float*)d_ws;

  k_front<<<dim3(32, 8), 512, 0, stream>>>(x, tw, tb, pw, pb, gw, gb, ws);
  k_attn_mfma<<<dim3(8, 32), 512, 0, stream>>>(x, Ww, Wb, ws, out);
}

// Round 19
// 108.541 us; speedup vs baseline: 2.5053x; 2.5053x over previous
//
#include <hip/hip_runtime.h>

// Workspace float offsets
#define F_TH    0u          // bf16 theta[8][4096][128]   -> 2,097,152 f
#define F_PHIB  2097152u    // bf16 phi[8][1024][128]     ->   524,288 f
#define F_GB    2621440u    // bf16 g[8][256][1024]       -> 1,048,576 f
// total 3,670,016 floats = 14.7 MB

typedef __attribute__((ext_vector_type(4))) float f32x4;
typedef __attribute__((ext_vector_type(8))) short bf16x8;

__device__ __forceinline__ unsigned short f2bf(float f) {
  union { unsigned int i; float f; } x; x.f = f;
  unsigned int r = x.i + 0x7fffu + ((x.i >> 16) & 1u);
  return (unsigned short)(r >> 16);
}
__device__ __forceinline__ unsigned int pk2(float a, float b) {
  return (unsigned int)f2bf(a) | ((unsigned int)f2bf(b) << 16);
}
__device__ __forceinline__ void gload_lds16(const void* g, void* l) {
  __builtin_amdgcn_global_load_lds(
      (const __attribute__((address_space(1))) unsigned int*)g,
      (__attribute__((address_space(3))) unsigned int*)l, 16, 0, 0);
}

// ---------------------------------------------------------------------------
// Fused front-end: x (f32 [b][512][4096]) -> theta[b][n][i] bf16,
// pooled phi[b][m][i] bf16, pooled g[b][d][m] bf16 — reads x exactly once.
// ---------------------------------------------------------------------------
__global__ __launch_bounds__(512)
void k_front(const float* __restrict__ x,
             const float* __restrict__ tw, const float* __restrict__ tb,
             const float* __restrict__ pw, const float* __restrict__ pb,
             const float* __restrict__ gw, const float* __restrict__ gb,
             float* __restrict__ ws) {
  const int nt = blockIdx.x, b = blockIdx.y;
  const int n0 = nt * 128;
  const int tid = threadIdx.x;
  const int w = tid >> 6, lane = tid & 63, q = lane >> 4, col = lane & 15;

  __shared__ uint4 ldsb[5888];      // 94,208 B
  char* lds = (char*)ldsb;
  char* xs  = lds;                  // [64 ch][512B] f32, swz ((ch&7)<<4)
  char* Xm  = lds + 32768;          // [128 n][80B] bf16 (32 c)
  char* Xg0 = lds + 43008;
  char* Xg1 = lds + 53248;
  char* Wt  = lds + 63488;          // [128 o][80B]
  char* Wp  = lds + 73728;
  char* Wg  = lds + 83968;

  f32x4 at[8], ap[8], a0[8], a1[8];
#pragma unroll
  for (int j = 0; j < 8; ++j) {
    at[j] = (f32x4){0.f, 0.f, 0.f, 0.f};
    ap[j] = (f32x4){0.f, 0.f, 0.f, 0.f};
    a0[j] = (f32x4){0.f, 0.f, 0.f, 0.f};
    a1[j] = (f32x4){0.f, 0.f, 0.f, 0.f};
  }

  for (int kc = 0; kc < 8; ++kc) {
    {
      const int ch = tid >> 5;               // 0..15
      const int so = (tid & 31) * 16;        // byte within 512B row
#pragma unroll
      for (int i = 0; i < 4; ++i) {
        const int chh = 16 * i + ch;
        const float* src = x + ((size_t)(b * 512 + 64 * kc + chh)) * 4096 + n0;
        gload_lds16((const char*)src + (so ^ ((chh & 7) << 4)),
                    xs + 8192 * i + tid * 16);
      }
      const int o = tid >> 2, c4 = tid & 3;
      const size_t wo = (size_t)o * 256 + 32 * kc + 8 * c4;
      float4 t0 = ((const float4*)(tw + wo))[0], t1 = ((const float4*)(tw + wo))[1];
      float4 p0 = ((const float4*)(pw + wo))[0], p1 = ((const float4*)(pw + wo))[1];
      float4 g0 = ((const float4*)(gw + wo))[0], g1 = ((const float4*)(gw + wo))[1];
      *(uint4*)(Wt + o * 80 + 16 * c4) =
          make_uint4(pk2(t0.x, t0.y), pk2(t0.z, t0.w), pk2(t1.x, t1.y), pk2(t1.z, t1.w));
      *(uint4*)(Wp + o * 80 + 16 * c4) =
          make_uint4(pk2(p0.x, p0.y), pk2(p0.z, p0.w), pk2(p1.x, p1.y), pk2(p1.z, p1.w));
      *(uint4*)(Wg + o * 80 + 16 * c4) =
          make_uint4(pk2(g0.x, g0.y), pk2(g0.z, g0.w), pk2(g1.x, g1.y), pk2(g1.z, g1.w));
    }
    __syncthreads();
    {
      const int n = tid >> 2, c4 = tid & 3;
      unsigned um[4], u0[4], u1[4];
#pragma unroll
      for (int s = 0; s < 4; ++s) {
        float v[4];
#pragma unroll
        for (int e = 0; e < 2; ++e) {
          const int cp = 8 * c4 + 2 * s + e;   // c' 0..31
          const int l0 = 2 * cp, l1 = 2 * cp + 1;
          v[2 * e]     = *(const float*)(xs + l0 * 512 + ((n * 4) ^ ((l0 & 7) << 4)));
          v[2 * e + 1] = *(const float*)(xs + l1 * 512 + ((n * 4) ^ ((l1 & 7) << 4)));
        }
        um[s] = pk2(0.5f * (v[0] + v[1]), 0.5f * (v[2] + v[3]));
        u0[s] = pk2(v[0], v[2]);
        u1[s] = pk2(v[1], v[3]);
      }
      *(uint4*)(Xm  + n * 80 + 16 * c4) = make_uint4(um[0], um[1], um[2], um[3]);
      *(uint4*)(Xg0 + n * 80 + 16 * c4) = make_uint4(u0[0], u0[1], u0[2], u0[3]);
      *(uint4*)(Xg1 + n * 80 + 16 * c4) = make_uint4(u1[0], u1[1], u1[2], u1[3]);
    }
    __syncthreads();
    {
      const int ar = 16 * w + col;
      const bf16x8 aft = *(const bf16x8*)(Wt + ar * 80 + 16 * q);
      const bf16x8 afp = *(const bf16x8*)(Wp + ar * 80 + 16 * q);
      const bf16x8 afg = *(const bf16x8*)(Wg + ar * 80 + 16 * q);
#pragma unroll
      for (int j = 0; j < 8; ++j) {
        const int br = 16 * j + col;
        const bf16x8 bm = *(const bf16x8*)(Xm  + br * 80 + 16 * q);
        const bf16x8 b0 = *(const bf16x8*)(Xg0 + br * 80 + 16 * q);
        const bf16x8 b1 = *(const bf16x8*)(Xg1 + br * 80 + 16 * q);
        at[j] = __builtin_amdgcn_mfma_f32_16x16x32_bf16(aft, bm, at[j], 0, 0, 0);
        ap[j] = __builtin_amdgcn_mfma_f32_16x16x32_bf16(afp, bm, ap[j], 0, 0, 0);
        a0[j] = __builtin_amdgcn_mfma_f32_16x16x32_bf16(afg, b0, a0[j], 0, 0, 0);
        a1[j] = __builtin_amdgcn_mfma_f32_16x16x32_bf16(afg, b1, a1[j], 0, 0, 0);
      }
    }
    __syncthreads();
  }

  const int o0 = 16 * w + 4 * q;
  const int mb = (nt >> 3) * 256 + (nt & 7) * 32;

  {
    float bst[4];
#pragma unroll
    for (int r = 0; r < 4; ++r) bst[r] = tb[o0 + r];
#pragma unroll
    for (int j = 0; j < 8; ++j) {
      const int n = 16 * j + col;
      uint2 pkk = make_uint2(pk2(at[j][0] + bst[0], at[j][1] + bst[1]),
                             pk2(at[j][2] + bst[2], at[j][3] + bst[3]));
      *(uint2*)(xs + n * 256 + ((2 * o0) ^ ((n & 7) << 4))) = pkk;
    }
  }

  {
    float bsp[4];
#pragma unroll
    for (int r = 0; r < 4; ++r) bsp[r] = pb[o0 + r];
    unsigned short* phiB = (unsigned short*)(ws + F_PHIB);
#pragma unroll
    for (int jj = 0; jj < 4; ++jj) {
      const int j = (jj >> 1) * 4 + (jj & 1);   // {0,1,4,5}
      f32x4 pm;
#pragma unroll
      for (int r = 0; r < 4; ++r) pm[r] = fmaxf(ap[j][r], ap[j + 2][r]);
#pragma unroll
      for (int r = 0; r < 4; ++r) pm[r] = fmaxf(pm[r], __shfl_xor(pm[r], 1));
      if ((col & 1) == 0) {
        const int vp = 8 * (j & 1) + (col >> 1);
        const int m = mb + 16 * (j >> 2) + vp;
        uint2 pkk = make_uint2(pk2(pm[0] + bsp[0], pm[1] + bsp[1]),
                               pk2(pm[2] + bsp[2], pm[3] + bsp[3]));
        *(uint2*)(phiB + ((size_t)(b * 1024) + m) * 128 + o0) = pkk;
      }
    }
  }

  {
    float bsg[4];
#pragma unroll
    for (int r = 0; r < 4; ++r) bsg[r] = gb[o0 + r];
#pragma unroll
    for (int gr = 0; gr < 2; ++gr) {
      char* pt = gr ? Xg1 : Xg0;
      const f32x4* ag = gr ? a1 : a0;
#pragma unroll
      for (int jj = 0; jj < 4; ++jj) {
        const int j = (jj >> 1) * 4 + (jj & 1);
        f32x4 pm;
#pragma unroll
        for (int r = 0; r < 4; ++r) pm[r] = fmaxf(ag[j][r], ag[j + 2][r]);
#pragma unroll
        for (int r = 0; r < 4; ++r) pm[r] = fmaxf(pm[r], __shfl_xor(pm[r], 1));
        if ((col & 1) == 0) {
          const int ml = 16 * (j >> 2) + 8 * (j & 1) + (col >> 1);
#pragma unroll
          for (int r = 0; r < 4; ++r)
            *(unsigned short*)(pt + (o0 + r) * 80 + ml * 2) = f2bf(pm[r] + bsg[r]);
        }
      }
    }
  }
  __syncthreads();

  {
    const int n = tid >> 2, seg = tid & 3;
    unsigned short* dst = (unsigned short*)(ws + F_TH) +
                          ((size_t)(b * 4096) + n0 + n) * 128 + seg * 32;
    const char* row = xs + n * 256;
    const int sw = (n & 7) << 4;
#pragma unroll
    for (int k = 0; k < 4; ++k)
      ((uint4*)dst)[k] = *(const uint4*)(row + ((64 * seg + 16 * k) ^ sw));
  }
  if (tid < 256) {
    const int o = tid >> 1, gr = tid & 1;
    const char* row = (gr ? Xg1 : Xg0) + o * 80;
    unsigned short* dst = (unsigned short*)(ws + F_GB) +
                          ((size_t)(b * 256) + 2 * o + gr) * 1024 + mb;
#pragma unroll
    for (int k = 0; k < 4; ++k)
      ((uint4*)dst)[k] = *(const uint4*)(row + 16 * k);
  }
}

// ---------------------------------------------------------------------------
// MFMA flash attention (R13 loop) + fused final W conv + bias + residual.
// Epilogue = R15 structure exactly (plain cached loads/stores; nt hints and
// register prefetch both measured as regressions in R16/R18).
// ---------------------------------------------------------------------------
#define NSIT 16
__global__ __launch_bounds__(512)
void k_attn_mfma(const float* __restrict__ x,
                 const float* __restrict__ Ww, const float* __restrict__ Wb,
                 float* __restrict__ ws, float* __restrict__ out) {
  const int b = blockIdx.x;          // 8 batches -> 8 XCDs (round-robin)
  const int n0 = blockIdx.y * 128;
  const int tid = threadIdx.x;
  const int w = tid >> 6;
  const int lane = tid & 63;
  const int q = lane >> 4;
  const int col = lane & 15;
  const int ksw = (col & 7) << 4;

  __shared__ char lds[131072];
  char* plw0 = lds + 98304 + w * 4096;
  char* plw1 = plw0 + 2048;

  const unsigned short* thetaB = (const unsigned short*)(ws + F_TH);
  const char* phiBb = (const char*)((const unsigned short*)(ws + F_PHIB) + (size_t)b * 1024 * 128);
  const char* gBb   = (const char*)((const unsigned short*)(ws + F_GB) + (size_t)b * 256 * 1024);

  const int kr0 = lane >> 4;
  const int kso = (lane & 15) * 16;
  const int vr0 = lane >> 3;
  const int vso = (lane & 7) * 16;

  bf16x8 qf[4];
  {
    const unsigned short* qp = thetaB + ((size_t)(b * 4096 + n0 + 16 * w + col)) * 128 + 8 * q;
#pragma unroll
    for (int c = 0; c < 4; ++c) qf[c] = *(const bf16x8*)(qp + 32 * c);
  }

  f32x4 ot[16];
#pragma unroll
  for (int t = 0; t < 16; ++t) ot[t] = (f32x4){0.f, 0.f, 0.f, 0.f};
  float mrun = -1e30f, lsum = 0.f;

  {
    const int r = 4 * w + kr0;
    gload_lds16(phiBb + (size_t)r * 256 + (kso ^ ((r & 7) << 4)), lds + w * 1024);
    gload_lds16(phiBb + (size_t)(32 + r) * 256 + (kso ^ ((r & 7) << 4)),
                lds + 8192 + w * 1024);
#pragma unroll
    for (int j = 0; j < 4; ++j) {
      const int c = 4 * w + j;
      const int d = 8 * c + vr0;
      gload_lds16(gBb + (size_t)d * 2048 + (vso ^ ((d & 7) << 4)),
                  lds + 32768 + c * 1024);
    }
  }
  __syncthreads();

  for (int sit = 0; sit < NSIT; ++sit) {
    char* kt0 = lds + ((2 * sit) & 3) * 8192;
    char* kt1 = lds + ((2 * sit + 1) & 3) * 8192;
    char* vtc = lds + 32768 + (sit & 1) * 32768;

    if (sit + 1 < NSIT) {
      const int r = 4 * w + kr0;
      const int swk = (kso ^ ((r & 7) << 4));
      gload_lds16(phiBb + (size_t)((2 * sit + 2) * 32 + r) * 256 + swk,
                  lds + ((2 * sit + 2) & 3) * 8192 + w * 1024);
      gload_lds16(phiBb + (size_t)((2 * sit + 3) * 32 + r) * 256 + swk,
                  lds + ((2 * sit + 3) & 3) * 8192 + w * 1024);
      const size_t vm = (size_t)((sit + 1) * 64) * 2;
#pragma unroll
      for (int j = 0; j < 4; ++j) {
        const int c = 4 * w + j;
        const int d = 8 * c + vr0;
        gload_lds16(gBb + (size_t)d * 2048 + vm + (vso ^ ((d & 7) << 4)),
                    lds + 32768 + ((sit & 1) ^ 1) * 32768 + c * 1024);
      }
    }

    f32x4 st0[2], st1[2];
#pragma unroll
    for (int s = 0; s < 2; ++s) {
      st0[s] = (f32x4){0.f, 0.f, 0.f, 0.f};
      st1[s] = (f32x4){0.f, 0.f, 0.f, 0.f};
    }
    __builtin_amdgcn_s_setprio(1);
#pragma unroll
    for (int c = 0; c < 4; ++c)
#pragma unroll
      for (int s = 0; s < 2; ++s) {
        const bf16x8 kf0 = *(const bf16x8*)(kt0 + (16 * s + col) * 256 +
                                            ((64 * c + 16 * q) ^ ksw));
        const bf16x8 kf1 = *(const bf16x8*)(kt1 + (16 * s + col) * 256 +
                                            ((64 * c + 16 * q) ^ ksw));
        st0[s] = __builtin_amdgcn_mfma_f32_16x16x32_bf16(kf0, qf[c], st0[s], 0, 0, 0);
        st1[s] = __builtin_amdgcn_mfma_f32_16x16x32_bf16(kf1, qf[c], st1[s], 0, 0, 0);
      }
    __builtin_amdgcn_s_setprio(0);

    float pmax = -1e30f;
#pragma unroll
    for (int s = 0; s < 2; ++s)
#pragma unroll
      for (int r = 0; r < 4; ++r) {
        pmax = fmaxf(pmax, st0[s][r]);
        pmax = fmaxf(pmax, st1[s][r]);
      }
    pmax = fmaxf(pmax, __shfl_xor(pmax, 16));
    pmax = fmaxf(pmax, __shfl_xor(pmax, 32));
    if (!__all(pmax - mrun <= 8.f)) {
      const float mnew = fmaxf(mrun, pmax);
      const float scl = __expf(mrun - mnew);
      mrun = mnew;
      lsum *= scl;
#pragma unroll
      for (int t = 0; t < 16; ++t) {
        ot[t][0] *= scl; ot[t][1] *= scl; ot[t][2] *= scl; ot[t][3] *= scl;
      }
    }
    float rsum = 0.f;
#pragma unroll
    for (int s = 0; s < 2; ++s)
#pragma unroll
      for (int r = 0; r < 4; ++r) {
        st0[s][r] = __expf(st0[s][r] - mrun);
        st1[s][r] = __expf(st1[s][r] - mrun);
        rsum += st0[s][r] + st1[s][r];
      }
    rsum += __shfl_xor(rsum, 16);
    rsum += __shfl_xor(rsum, 32);
    lsum += rsum;

    char* prow0 = plw0 + col * 128;
    char* prow1 = plw1 + col * 128;
#pragma unroll
    for (int s = 0; s < 2; ++s)
#pragma unroll
      for (int hp = 0; hp < 2; ++hp) {
        *(unsigned int*)(prow0 + ((32 * s + 8 * q + 4 * hp) ^ ksw)) =
            pk2(st0[s][2 * hp], st0[s][2 * hp + 1]);
        *(unsigned int*)(prow1 + ((32 * s + 8 * q + 4 * hp) ^ ksw)) =
            pk2(st1[s][2 * hp], st1[s][2 * hp + 1]);
      }
    const bf16x8 pf0 = *(const bf16x8*)(prow0 + ((16 * q) ^ ksw));
    const bf16x8 pf1 = *(const bf16x8*)(prow1 + ((16 * q) ^ ksw));

    __builtin_amdgcn_s_setprio(1);
#pragma unroll
    for (int t = 0; t < 16; ++t) {
      const int d = 16 * t + col;
      const int dsw = (d & 7) << 4;
      const bf16x8 vf0 = *(const bf16x8*)(vtc + d * 128 + ((16 * q) ^ dsw));
      ot[t] = __builtin_amdgcn_mfma_f32_16x16x32_bf16(vf0, pf0, ot[t], 0, 0, 0);
    }
#pragma unroll
    for (int t = 0; t < 16; ++t) {
      const int d = 16 * t + col;
      const int dsw = (d & 7) << 4;
      const bf16x8 vf1 = *(const bf16x8*)(vtc + d * 128 + ((64 + 16 * q) ^ dsw));
      ot[t] = __builtin_amdgcn_mfma_f32_16x16x32_bf16(vf1, pf1, ot[t], 0, 0, 0);
    }
    __builtin_amdgcn_s_setprio(0);

    __syncthreads();
  }

  // ---- write normalized y tile to LDS (B-fragment layout) ----
  const float inv = 1.f / lsum;
  char* yt = lds;
  {
    const int nl = 16 * w + col;
    const int swn = (nl & 7) << 4;
#pragma unroll
    for (int t = 0; t < 16; ++t) {
      const unsigned int w0 = pk2(ot[t][0] * inv, ot[t][2] * inv);
      const unsigned int w1 = pk2(ot[t][1] * inv, ot[t][3] * inv);
      const int bo = 16 * t + 4 * q;
      *(unsigned int*)(yt + nl * 256 + (bo ^ swn)) = w0;
      *(unsigned int*)(yt + (128 + nl) * 256 + (bo ^ swn)) = w1;
    }
  }
  __syncthreads();

  // ---- fused W conv: facc[gr][h][j] = sum_i Ww[32w+16h+col][i] * y[gr][n][i]
  f32x4 facc[2][2][8];
#pragma unroll
  for (int gr = 0; gr < 2; ++gr)
#pragma unroll
    for (int h = 0; h < 2; ++h)
#pragma unroll
      for (int j = 0; j < 8; ++j) facc[gr][h][j] = (f32x4){0.f, 0.f, 0.f, 0.f};

#pragma unroll
  for (int gr = 0; gr < 2; ++gr) {
#pragma unroll
    for (int c = 0; c < 4; ++c) {
      bf16x8 bfr[8];
#pragma unroll
      for (int j = 0; j < 8; ++j) {
        const int nl = 16 * j + col;
        bfr[j] = *(const bf16x8*)(yt + (128 * gr + nl) * 256 + ((64 * c + 16 * q) ^ ksw));
      }
#pragma unroll
      for (int h = 0; h < 2; ++h) {
        const int o = 32 * w + 16 * h + col;
        const float* wp = Ww + (size_t)o * 128 + 32 * c + 8 * q;
        const float4 w0 = ((const float4*)wp)[0];
        const float4 w1 = ((const float4*)wp)[1];
        union { unsigned u[4]; bf16x8 v; } af;
        af.u[0] = pk2(w0.x, w0.y); af.u[1] = pk2(w0.z, w0.w);
        af.u[2] = pk2(w1.x, w1.y); af.u[3] = pk2(w1.z, w1.w);
#pragma unroll
        for (int j = 0; j < 8; ++j)
          facc[gr][h][j] = __builtin_amdgcn_mfma_f32_16x16x32_bf16(af.v, bfr[j], facc[gr][h][j], 0, 0, 0);
      }
    }
  }
  __syncthreads();   // all waves done reading yt; LDS free for f32 transpose

  // ---- per-group f32 transpose + bias + residual + coalesced store ----
  char* ft = lds;    // [256 o][512B], swz ((o&7)<<4)  = 128KB
#pragma unroll
  for (int gr = 0; gr < 2; ++gr) {
#pragma unroll
    for (int h = 0; h < 2; ++h) {
      const int o0 = 32 * w + 16 * h + 4 * q;
#pragma unroll
      for (int j = 0; j < 8; ++j) {
        const int n = 16 * j + col;
#pragma unroll
        for (int r = 0; r < 4; ++r)
          *(float*)(ft + (o0 + r) * 512 + ((n * 4) ^ (((o0 + r) & 7) << 4))) =
              facc[gr][h][j][r];
      }
    }
    __syncthreads();
    {
      const int o = tid >> 1, h2 = tid & 1;
      const float bsv = Wb[o];
      const int ch = 2 * o + gr;
      const size_t base = ((size_t)(b * 512 + ch)) * 4096 + n0 + h2 * 64;
      const char* row = ft + o * 512;
      const int sw = (o & 7) << 4;
#pragma unroll
      for (int k = 0; k < 16; ++k) {
        f32x4 v = *(const f32x4*)(row + ((256 * h2 + 16 * k) ^ sw));
        const float4 xa = ((const float4*)(x + base))[k];
        ((float4*)(out + base))[k] = make_float4(v[0] + bsv + xa.x, v[1] + bsv + xa.y,
                                                 v[2] + bsv + xa.z, v[3] + bsv + xa.w);
      }
    }
    if (gr == 0) __syncthreads();
  }
}

extern "C" void kernel_launch(void* const* d_in, const int* in_sizes, int n_in,
                              void* d_out, int out_size, void* d_ws, size_t ws_size,
                              hipStream_t stream) {
  const float* x  = (const float*)d_in[0];
  const float* gw = (const float*)d_in[1];
  const float* gb = (const float*)d_in[2];
  const float* tw = (const float*)d_in[3];
  const float* tb = (const float*)d_in[4];
  const float* pw = (const float*)d_in[5];
  const float* pb = (const float*)d_in[6];
  const float* Ww = (const float*)d_in[7];
  const float* Wb = (const float*)d_in[8];
  float* out = (float*)d_out;
  float* ws  = (float*)d_ws;

  k_front<<<dim3(32, 8), 512, 0, stream>>>(x, tw, tb, pw, pb, gw, gb, ws);
  k_attn_mfma<<<dim3(8, 32), 512, 0, stream>>>(x, Ww, Wb, ws, out);
}